// Round 3
// baseline (1130.652 us; speedup 1.0000x reference)
//
#include <hip/hip_runtime.h>

#define T_TOKENS 32768
#define DIM      2048
#define NEXP     64
#define KC       64
#define NCHUNK   (DIM / KC)      // 32
#define TPB      256
#define TOK_BLK  64
#define LSTR     65              // 64 + 1 pad: conflict-free transposed reads

__global__ __launch_bounds__(TPB, 2) void router_kernel(
    const float* __restrict__ hs, const float* __restrict__ w,
    float* __restrict__ logits, float* __restrict__ tkp, float* __restrict__ tki)
{
    __shared__ float lds[2][KC * LSTR];     // 2 x 64x65 f32 = 33.3 KB

    const int tid  = threadIdx.x;
    const int lane = tid & 63;
    const int wv   = __builtin_amdgcn_readfirstlane(tid >> 6);
    const int ebase = wv * 16;
    const int t0   = blockIdx.x * TOK_BLK;

    float acc[16];
#pragma unroll
    for (int i = 0; i < 16; ++i) acc[i] = 0.f;

    float4 st[4];

    // ---- stage chunk 0 (transposed into lds[0]) ----
#pragma unroll
    for (int i = 0; i < 4; ++i) {
        int f = i * TPB + tid, row = f >> 4, c4 = f & 15;
        st[i] = *(const float4*)(hs + (size_t)(t0 + row) * DIM + c4 * 4);
    }
#pragma unroll
    for (int i = 0; i < 4; ++i) {
        int f = i * TPB + tid, row = f >> 4, c4 = f & 15;
        lds[0][(c4 * 4 + 0) * LSTR + row] = st[i].x;
        lds[0][(c4 * 4 + 1) * LSTR + row] = st[i].y;
        lds[0][(c4 * 4 + 2) * LSTR + row] = st[i].z;
        lds[0][(c4 * 4 + 3) * LSTR + row] = st[i].w;
    }
    __syncthreads();

#pragma unroll 1
    for (int kc = 0; kc < NCHUNK; ++kc) {
        const int buf = kc & 1;

        // prefetch next chunk into regs (latency hides under FMA block)
        if (kc + 1 < NCHUNK) {
#pragma unroll
            for (int i = 0; i < 4; ++i) {
                int f = i * TPB + tid, row = f >> 4, c4 = f & 15;
                st[i] = *(const float4*)(hs + (size_t)(t0 + row) * DIM +
                                         (kc + 1) * KC + c4 * 4);
            }
        }

        // compute: 1024 FMAs/thread; weights are wave-uniform -> s_load + SGPR fmac operand
        const float* wbase = w + (size_t)ebase * DIM + kc * KC;
#pragma unroll
        for (int k4 = 0; k4 < 16; ++k4) {
            float h0 = lds[buf][(k4 * 4 + 0) * LSTR + lane];
            float h1 = lds[buf][(k4 * 4 + 1) * LSTR + lane];
            float h2 = lds[buf][(k4 * 4 + 2) * LSTR + lane];
            float h3 = lds[buf][(k4 * 4 + 3) * LSTR + lane];
#pragma unroll
            for (int e = 0; e < 16; ++e) {
                const float* wr = wbase + e * DIM + k4 * 4;
                acc[e] = fmaf(h0, wr[0], acc[e]);
                acc[e] = fmaf(h1, wr[1], acc[e]);
                acc[e] = fmaf(h2, wr[2], acc[e]);
                acc[e] = fmaf(h3, wr[3], acc[e]);
            }
        }

        // write next chunk to the other buffer (prev reads of it finished last barrier)
        if (kc + 1 < NCHUNK) {
#pragma unroll
            for (int i = 0; i < 4; ++i) {
                int f = i * TPB + tid, row = f >> 4, c4 = f & 15;
                lds[buf ^ 1][(c4 * 4 + 0) * LSTR + row] = st[i].x;
                lds[buf ^ 1][(c4 * 4 + 1) * LSTR + row] = st[i].y;
                lds[buf ^ 1][(c4 * 4 + 2) * LSTR + row] = st[i].z;
                lds[buf ^ 1][(c4 * 4 + 3) * LSTR + row] = st[i].w;
            }
        }
        __syncthreads();
    }

    // ---- epilogue: logits out + stash tile to LDS for top-2 ----
    float* ltile = &lds[0][0];              // reuse as [64 tok][stride 65]
#pragma unroll
    for (int i = 0; i < 4; ++i) {
        *(float4*)(logits + (size_t)(t0 + lane) * NEXP + ebase + i * 4) =
            make_float4(acc[i * 4 + 0], acc[i * 4 + 1], acc[i * 4 + 2], acc[i * 4 + 3]);
    }
#pragma unroll
    for (int i = 0; i < 16; ++i)
        ltile[lane * LSTR + ebase + i] = acc[i];
    __syncthreads();

    if (tid < TOK_BLK) {
        const int t = tid;
        float m1 = -1e30f; int i1 = 0;
#pragma unroll
        for (int e = 0; e < NEXP; ++e) {
            float v = ltile[t * LSTR + e];
            if (v > m1) { m1 = v; i1 = e; }   // strict > keeps earliest index (stable)
        }
        float m2 = -1e30f; int i2 = 0;
#pragma unroll
        for (int e = 0; e < NEXP; ++e) {
            float v = ltile[t * LSTR + e];
            if (e != i1 && v > m2) { m2 = v; i2 = e; }
        }
        // topk_prob renormalized: denominator of softmax cancels
        float e2v = __expf(m2 - m1);
        float s = 1.f + e2v;
        tkp[(size_t)(t0 + t) * 2 + 0] = 1.f / s;
        tkp[(size_t)(t0 + t) * 2 + 1] = e2v / s;
        // harness reads the whole concatenated d_out as float32 -> store idx as float
        tki[(size_t)(t0 + t) * 2 + 0] = (float)i1;
        tki[(size_t)(t0 + t) * 2 + 1] = (float)i2;
    }
}

extern "C" void kernel_launch(void* const* d_in, const int* in_sizes, int n_in,
                              void* d_out, int out_size, void* d_ws, size_t ws_size,
                              hipStream_t stream) {
    const float* hs = (const float*)d_in[0];
    const float* w  = (const float*)d_in[1];
    float* logits = (float*)d_out;
    float* tkp    = logits + (size_t)T_TOKENS * NEXP;
    float* tki    = tkp + (size_t)T_TOKENS * 2;

    dim3 grid(T_TOKENS / TOK_BLK);   // 512 blocks
    router_kernel<<<grid, TPB, 0, stream>>>(hs, w, logits, tkp, tki);
}